// Round 3
// baseline (257.350 us; speedup 1.0000x reference)
//
#include <hip/hip_runtime.h>
#include <hip/hip_bf16.h>

#define NODES_DIM 64   // H*D = 4*16
#define SL_DIM    12   // H*DC = 4*3
#define CAP       64   // bucket capacity; deg ~ Poisson(16), P(>=64) ~ 1e-18

// round-to-nearest-even fp32 -> bf16
__device__ __forceinline__ unsigned short f2bf(float f) {
    union { float f; unsigned u; } x; x.f = f;
    const unsigned r = x.u + 0x7FFFu + ((x.u >> 16) & 1u);
    return (unsigned short)(r >> 16);
}

// ---------------------------------------------------------------------------
// Persistent fused kernel with WAVE-LEVEL WORK-STEALING.
// grid = 768 (256 CU x 3 resident, LDS-bound at 48 KB). Each block stages W
// into LDS once; then each WAVE independently steals tiles from a global
// atomic counter. Tile = 8 GEMM rows + 128 edges (N/8 = E/128 = 6250 tiles,
// exact). Stealing fixes R2's static-stride tail (27/768 blocks ran the last
// third alone) and desynchronizes waves so lgkmcnt waits of one wave overlap
// FMAs of others (R2 convoy: VALUBusy 18%).
// GEMM inner loop: explicit 2-deep register prefetch of the wave-uniform h
// rows (named hA/hB buffers, static indices) -> the wait before each k4's
// 96 FMAs covers loads issued one iteration earlier.
// Fill pipeline: edge loads at tile top (hidden under GEMM), atomicAdd at
// tile end, dependent list-store drained after the NEXT tile's GEMM.
// Next tile index is also fetched pre-GEMM and consumed post-GEMM.
// ---------------------------------------------------------------------------
__global__ __launch_bounds__(256, 4) void qkv_fill_kernel(
    const float* __restrict__ h,
    const float* __restrict__ Wq, const float* __restrict__ bq,
    const float* __restrict__ Wk, const float* __restrict__ bk,
    const float* __restrict__ Wv, const float* __restrict__ bv,
    float* __restrict__ Q, unsigned* __restrict__ KV, int N,
    const int* __restrict__ src, const int* __restrict__ dst,
    int* __restrict__ cursor, int* __restrict__ list, int E,
    int NTT, int* __restrict__ tctr)
{
    __shared__ float sW[3][64][64];   // [mat][k][c], 48 KB -> 3 blocks/CU

    const int tid  = threadIdx.x;
    const int lane = tid & 63;

    // ---- stage W once per block, float4 vectorized ----
    {
        float4* lf = (float4*)(&sW[0][0][0]);
        const float4* gq = (const float4*)Wq;   // 1024 float4 each
        const float4* gk = (const float4*)Wk;
        const float4* gv = (const float4*)Wv;
        for (int i = tid; i < 1024; i += 256) {
            lf[i]        = gq[i];
            lf[i + 1024] = gk[i];
            lf[i + 2048] = gv[i];
        }
    }
    __syncthreads();   // only barrier; sW read-only afterwards

    const int c = lane;
    const float bqc = bq[c], bkc = bk[c], bvc = bv[c];

    // carried fill state (software pipeline across tiles)
    int cpos0 = -1, csv0 = 0;  size_t cdv0 = 0;
    int cpos1 = -1, csv1 = 0;  size_t cdv1 = 0;

    // initial steal (exposed once per wave)
    int t_raw = 0;
    if (lane == 0) t_raw = atomicAdd(tctr, 1);
    int t = __builtin_amdgcn_readfirstlane(t_raw);

    while (t < NTT) {
        // -------- steal NEXT tile index early; consumed after the GEMM -----
        int tn_raw = 0;
        if (lane == 0) tn_raw = atomicAdd(tctr, 1);

        // -------- edge loads for this tile (2/lane, coalesced) -------------
        const int e0 = t * 128 + lane;
        const int e1 = e0 + 64;
        const bool ok0 = e0 < E;
        const bool ok1 = e1 < E;
        const int sv0 = ok0 ? src[e0] : 0;
        const int dv0 = ok0 ? dst[e0] : 0;
        const int sv1 = ok1 ? src[e1] : 0;
        const int dv1 = ok1 ? dst[e1] : 0;

        // -------- 8-row GEMM for this tile ---------------------------------
        const int rowBase = t * 8;
        if (rowBase < N) {
            float acc0[8], acc1[8], acc2[8];
#pragma unroll
            for (int rr = 0; rr < 8; ++rr) { acc0[rr] = 0.f; acc1[rr] = 0.f; acc2[rr] = 0.f; }

            const int nrows = (N - rowBase < 8) ? (N - rowBase) : 8;
            if (nrows == 8) {
                // wave-uniform base (rowBase is SGPR via readfirstlane chain)
                const float4* hb = (const float4*)(h + (size_t)rowBase * 64);
                float4 hA[8], hB[8];
#pragma unroll
                for (int rr = 0; rr < 8; ++rr) hA[rr] = hb[rr * 16];

#define QKV_COMPUTE(BUF, K4)                                          \
                {                                                     \
                    _Pragma("unroll")                                 \
                    for (int kk = 0; kk < 4; ++kk) {                  \
                        const int k = (K4) * 4 + kk;                  \
                        const float wq = sW[0][k][c];                 \
                        const float wk = sW[1][k][c];                 \
                        const float wv = sW[2][k][c];                 \
                        _Pragma("unroll")                             \
                        for (int rr = 0; rr < 8; ++rr) {              \
                            const float hh = (&BUF[rr].x)[kk];        \
                            acc0[rr] += hh * wq;                      \
                            acc1[rr] += hh * wk;                      \
                            acc2[rr] += hh * wv;                      \
                        }                                             \
                    }                                                 \
                }

                for (int k4 = 0; k4 < 16; k4 += 2) {
#pragma unroll
                    for (int rr = 0; rr < 8; ++rr) hB[rr] = hb[rr * 16 + k4 + 1];
                    QKV_COMPUTE(hA, k4)
                    if (k4 + 2 < 16) {
#pragma unroll
                        for (int rr = 0; rr < 8; ++rr) hA[rr] = hb[rr * 16 + k4 + 2];
                    }
                    QKV_COMPUTE(hB, k4 + 1)
                }
            } else {
                // tail path (never taken for N%8==0; kept for generality)
                for (int k4 = 0; k4 < 16; ++k4) {
                    float4 hv[8];
#pragma unroll
                    for (int rr = 0; rr < 8; ++rr)
                        hv[rr] = (rr < nrows)
                            ? ((const float4*)(h + (size_t)(rowBase + rr) * 64))[k4]
                            : make_float4(0.f, 0.f, 0.f, 0.f);
                    QKV_COMPUTE(hv, k4)
                }
            }

#pragma unroll
            for (int rr = 0; rr < 8; ++rr) {
                if (rr < nrows) {
                    const size_t o = (size_t)(rowBase + rr) * 64 + c;
                    Q[o] = acc0[rr] + bqc;
                    const unsigned short kb = f2bf(acc1[rr] + bkc);
                    const unsigned short vb = f2bf(acc2[rr] + bvc);
                    KV[o] = ((unsigned)vb << 16) | (unsigned)kb;
                }
            }
        }

        // -------- drain PREVIOUS tile's atomics (long since returned) ------
        if (cpos0 >= 0 && cpos0 < CAP) list[(cdv0 << 6) + cpos0] = csv0;
        if (cpos1 >= 0 && cpos1 < CAP) list[(cdv1 << 6) + cpos1] = csv1;

        // -------- issue THIS tile's atomics; consumed next iteration -------
        cpos0 = ok0 ? atomicAdd(&cursor[dv0], 1) : -1;
        csv0 = sv0; cdv0 = (size_t)dv0;
        cpos1 = ok1 ? atomicAdd(&cursor[dv1], 1) : -1;
        csv1 = sv1; cdv1 = (size_t)dv1;

        // -------- consume the stolen next-tile index (atomic now complete) -
        t = __builtin_amdgcn_readfirstlane(tn_raw);
    }

    // final drain
    if (cpos0 >= 0 && cpos0 < CAP) list[(cdv0 << 6) + cpos0] = csv0;
    if (cpos1 >= 0 && cpos1 < CAP) list[(cdv1 << 6) + cpos1] = csv1;
}

// ---------------------------------------------------------------------------
// Node phase, edge-quad layout (unchanged). One wave per node.
// lane = e2*16 + head*4 + quad. Per 4-edge group: 1 dwordx4 KV load/lane,
// width-4 2-stage shfl reduce, exp amortized, V accumulated in-lane.
// ---------------------------------------------------------------------------
__global__ __launch_bounds__(256) void node_kernel(
    const float* __restrict__ Q, const unsigned* __restrict__ KV,
    const float* __restrict__ s_l,
    const int* __restrict__ cursor, const int* __restrict__ list,
    float* __restrict__ out, int N)
{
    const int t = blockIdx.x * 256 + threadIdx.x;
    const int node = t >> 6;
    if (node >= N) return;
    const int lane = threadIdx.x & 63;
    const int e2   = lane >> 4;
    const int hq   = lane & 15;
    const int head = hq >> 2;
    const int quad = hq & 3;

    int deg = cursor[node];
    deg = (deg > CAP) ? CAP : deg;

    const float4 qv = *(const float4*)(Q + (size_t)node * 64 + (hq << 2));
    const float slv = (quad < 3) ? s_l[(size_t)node * SL_DIM + head * 3 + quad] : 0.f;

    const int* lbase = list + ((size_t)node << 6);

    float4 accV = make_float4(0.f, 0.f, 0.f, 0.f);
    float zs = 0.f;

    const int ng = (deg + 3) >> 2;
#pragma unroll 2
    for (int i = 0; i < ng; ++i) {
        const int slot  = (i << 2) + e2;
        const bool valid = slot < deg;
        const int sidx  = lbase[valid ? slot : 0];

        const uint4 kv = *(const uint4*)(KV + (size_t)sidx * 64 + (hq << 2));
        const float a  = (quad < 3) ? s_l[(size_t)sidx * SL_DIM + head * 3 + quad] : 0.f;

        float dt = __uint_as_float(kv.x << 16) * qv.x
                 + __uint_as_float(kv.y << 16) * qv.y
                 + __uint_as_float(kv.z << 16) * qv.z
                 + __uint_as_float(kv.w << 16) * qv.w;
        const float df = a - slv;
        float ds = df * df;

        dt += __shfl_xor(dt, 1, 4);
        dt += __shfl_xor(dt, 2, 4);
        ds += __shfl_xor(ds, 1, 4);
        ds += __shfl_xor(ds, 2, 4);

        const float sc = fminf(fmaxf(dt * 0.25f, -5.f), 5.f);
        float score = __expf(sc);
        score = valid ? score : 0.f;
        const float w    = __expf(-ds * ds);
        const float news = score * w;
        zs += score;

        accV.x += __uint_as_float(kv.x & 0xFFFF0000u) * news;
        accV.y += __uint_as_float(kv.y & 0xFFFF0000u) * news;
        accV.z += __uint_as_float(kv.z & 0xFFFF0000u) * news;
        accV.w += __uint_as_float(kv.w & 0xFFFF0000u) * news;
    }

#pragma unroll
    for (int m = 16; m <= 32; m <<= 1) {
        accV.x += __shfl_xor(accV.x, m);
        accV.y += __shfl_xor(accV.y, m);
        accV.z += __shfl_xor(accV.z, m);
        accV.w += __shfl_xor(accV.w, m);
        zs     += __shfl_xor(zs, m);
    }

    if (e2 == 0) {
        const float inv = (zs > 0.f) ? (1.f / zs) : 1.f;
        float4 o;
        o.x = accV.x * inv; o.y = accV.y * inv;
        o.z = accV.z * inv; o.w = accV.w * inv;
        *(float4*)(out + (size_t)node * 64 + (hq << 2)) = o;
    }
}

extern "C" void kernel_launch(void* const* d_in, const int* in_sizes, int n_in,
                              void* d_out, int out_size, void* d_ws, size_t ws_size,
                              hipStream_t stream) {
    const float* h   = (const float*)d_in[0];
    const float* s_l = (const float*)d_in[1];
    const float* Wq  = (const float*)d_in[2];
    const float* bq  = (const float*)d_in[3];
    const float* Wk  = (const float*)d_in[4];
    const float* bk  = (const float*)d_in[5];
    const float* Wv  = (const float*)d_in[6];
    const float* bv  = (const float*)d_in[7];
    const int*   src = (const int*)d_in[8];
    const int*   dst = (const int*)d_in[9];
    float* out = (float*)d_out;

    const int N = in_sizes[0] / 64;   // 50000
    const int E = in_sizes[8];        // 800000

    // workspace: Q fp32 (N*64) | KV packed (N*64) | cursor (N) | tctr+pad (16)
    //            | list (N*CAP)
    float*    Q      = (float*)d_ws;
    unsigned* KV     = (unsigned*)(Q + (size_t)N * NODES_DIM);
    int*      cursor = (int*)(KV + (size_t)N * NODES_DIM);
    int*      tctr   = cursor + N;
    int*      list   = cursor + N + 16;

    // one memset covers cursor + tile counter
    hipMemsetAsync(cursor, 0, ((size_t)N + 16) * sizeof(int), stream);

    // tiles: 8 rows + 128 edges each; N/8 = E/128 = 6250 (exact)
    const int NT_rows  = (N + 7) / 8;
    const int NT_edges = (E + 127) / 128;
    const int NTT = (NT_rows > NT_edges) ? NT_rows : NT_edges;

    int grid = 768;                    // 3 blocks/CU, all co-resident
    if (grid > NTT) grid = NTT;

    qkv_fill_kernel<<<grid, 256, 0, stream>>>(
        h, Wq, bq, Wk, bk, Wv, bv, Q, KV, N,
        src, dst, cursor, list, E, NTT, tctr);

    const long long nthreads = (long long)N * 64;
    node_kernel<<<(int)((nthreads + 255) / 256), 256, 0, stream>>>(
        Q, KV, s_l, cursor, list, out, N);
}

// Round 4
// 193.675 us; speedup vs baseline: 1.3288x; 1.3288x over previous
//
#include <hip/hip_runtime.h>
#include <hip/hip_bf16.h>

#define NODES_DIM 64   // H*D = 4*16
#define SL_DIM    12   // H*DC = 4*3
#define CAP       64   // bucket capacity; deg ~ Poisson(16), P(>=64) ~ 1e-18

// round-to-nearest-even fp32 -> bf16
__device__ __forceinline__ unsigned short f2bf(float f) {
    union { float f; unsigned u; } x; x.f = f;
    const unsigned r = x.u + 0x7FFFu + ((x.u >> 16) & 1u);
    return (unsigned short)(r >> 16);
}

// ---------------------------------------------------------------------------
// R0 heterogeneous skeleton (best measured: 58 us) with ONE change: the
// GEMM's h access. R0 loaded h wave-uniformly (scalar path, 128 loads/tile,
// lgkmcnt-serialized with weight ds_reads -> VALUBusy 25%, latency-bound).
// Now: the wave's 8x64 h tile (128 float4) is loaded by TWO coalesced
// per-lane float4 loads (lane L owns float4 #L and #(64+L)); element
// h[rr][k] is broadcast from lane (rr&3)*16 + (k>>2) via v_readlane, whose
// SGPR result feeds v_fmac directly. Steady loop = 12 ds_read + 32 readlane
// + 96 fmac per k4: no memory stalls. No extra LDS -> still 3 blocks/CU.
// Roles by blockIdx%3: r in {0,1} -> QKV (VALU-bound), r==2 -> edge-bucket
// fill (atomic/latency-bound). Disjoint pipes overlap on co-resident CUs.
// ---------------------------------------------------------------------------
__global__ __launch_bounds__(256) void qkv_fill_kernel(
    const float* __restrict__ h,
    const float* __restrict__ Wq, const float* __restrict__ bq,
    const float* __restrict__ Wk, const float* __restrict__ bk,
    const float* __restrict__ Wv, const float* __restrict__ bv,
    float* __restrict__ Q, unsigned* __restrict__ KV, int N,
    const int* __restrict__ src, const int* __restrict__ dst,
    int* __restrict__ cursor, int* __restrict__ list, int E)
{
    __shared__ float sW[3][64][64];   // 48 KB (qkv role only)

    const int r = blockIdx.x % 3;
    const int g = blockIdx.x / 3;

    if (r == 2) {
        // ---------------- fill role (verbatim from the 58 us R0) ----------
        const int e0 = g * 1024 + threadIdx.x;
        int sv[4], dv[4];
        bool ok[4];
#pragma unroll
        for (int j = 0; j < 4; ++j) {
            const int e = e0 + j * 256;
            ok[j] = e < E;
            sv[j] = ok[j] ? src[e] : 0;
            dv[j] = ok[j] ? dst[e] : 0;
        }
#pragma unroll
        for (int j = 0; j < 4; ++j) {
            if (ok[j]) {
                const int pos = atomicAdd(&cursor[dv[j]], 1);
                if (pos < CAP) list[((size_t)dv[j] << 6) + pos] = sv[j];
            }
        }
        return;
    }

    // ---------------- qkv role ----------------
    const int qb = g * 2 + r;
    const int rowBase0 = qb * 32;
    if (rowBase0 >= N) return;

    const int c    = threadIdx.x & 63;
    const int slot = __builtin_amdgcn_readfirstlane((int)(threadIdx.x >> 6));
    const int rowBase = rowBase0 + slot * 8;
    const int lane = c;

    // ---- per-lane h tile loads, issued BEFORE staging so the ~600cy HBM
    //      latency hides under the W staging + barrier ----
    float4 a4 = make_float4(0.f, 0.f, 0.f, 0.f);
    float4 b4 = make_float4(0.f, 0.f, 0.f, 0.f);
    if (rowBase < N) {
        const int nrows = (N - rowBase < 8) ? (N - rowBase) : 8;
        if (nrows == 8) {
            const float4* hb = (const float4*)(h + (size_t)rowBase * 64);
            a4 = hb[lane];        // rows 0..3 : rr = lane>>4, k4 = lane&15
            b4 = hb[64 + lane];   // rows 4..7
        } else {
            // tail: clamp rows so addresses stay in-bounds; bad rr discarded
            int r0 = lane >> 4;       if (r0 > nrows - 1) r0 = nrows - 1;
            int r1 = 4 + (lane >> 4); if (r1 > nrows - 1) r1 = nrows - 1;
            const int kq = lane & 15;
            a4 = ((const float4*)(h + (size_t)(rowBase + r0) * 64))[kq];
            b4 = ((const float4*)(h + (size_t)(rowBase + r1) * 64))[kq];
        }
    }

    // ---- stage W into LDS, float4-vectorized ----
    {
        float4* lf = (float4*)(&sW[0][0][0]);
        const float4* gq = (const float4*)Wq;   // 1024 float4 each
        const float4* gk = (const float4*)Wk;
        const float4* gv = (const float4*)Wv;
        for (int i = threadIdx.x; i < 1024; i += 256) {
            lf[i]        = gq[i];
            lf[i + 1024] = gk[i];
            lf[i + 2048] = gv[i];
        }
    }
    __syncthreads();

    if (rowBase >= N) return;
    const int nrows = (N - rowBase < 8) ? (N - rowBase) : 8;

    const float hA0 = a4.x, hA1 = a4.y, hA2 = a4.z, hA3 = a4.w;
    const float hB0 = b4.x, hB1 = b4.y, hB2 = b4.z, hB3 = b4.w;

    float acc0[8], acc1[8], acc2[8];
#pragma unroll
    for (int rr = 0; rr < 8; ++rr) { acc0[rr] = 0.f; acc1[rr] = 0.f; acc2[rr] = 0.f; }

    // broadcast h[rr][k4*4+kk] from lane (rr&3)*16 + k4, component kk
#define HCOMP(RR, KK) ((RR) < 4 ? ((KK)==0 ? hA0 : (KK)==1 ? hA1 : (KK)==2 ? hA2 : hA3) \
                                 : ((KK)==0 ? hB0 : (KK)==1 ? hB1 : (KK)==2 ? hB2 : hB3))

    for (int k4 = 0; k4 < 16; ++k4) {
        float wqv[4], wkv[4], wvv[4];
#pragma unroll
        for (int kk = 0; kk < 4; ++kk) {
            const int k = k4 * 4 + kk;
            wqv[kk] = sW[0][k][c];
            wkv[kk] = sW[1][k][c];
            wvv[kk] = sW[2][k][c];
        }
#pragma unroll
        for (int kk = 0; kk < 4; ++kk) {
#pragma unroll
            for (int rr = 0; rr < 8; ++rr) {
                const int srclane = (rr & 3) * 16 + k4;   // uniform (SGPR)
                const float hh = __int_as_float(
                    __builtin_amdgcn_readlane(__float_as_int(HCOMP(rr, kk)), srclane));
                acc0[rr] += hh * wqv[kk];
                acc1[rr] += hh * wkv[kk];
                acc2[rr] += hh * wvv[kk];
            }
        }
    }
#undef HCOMP

    const float bqc = bq[c], bkc = bk[c], bvc = bv[c];
#pragma unroll
    for (int rr = 0; rr < 8; ++rr) {
        if (rr < nrows) {
            const size_t o = (size_t)(rowBase + rr) * 64 + c;
            Q[o] = acc0[rr] + bqc;
            const unsigned short kb = f2bf(acc1[rr] + bkc);
            const unsigned short vb = f2bf(acc2[rr] + bvc);
            KV[o] = ((unsigned)vb << 16) | (unsigned)kb;
        }
    }
}

// ---------------------------------------------------------------------------
// Node phase, edge-quad layout (unchanged from R0). One wave per node.
// lane = e2*16 + head*4 + quad. Per 4-edge group: 1 dwordx4 KV load/lane,
// width-4 2-stage shfl reduce, exp amortized, V accumulated in-lane.
// ---------------------------------------------------------------------------
__global__ __launch_bounds__(256) void node_kernel(
    const float* __restrict__ Q, const unsigned* __restrict__ KV,
    const float* __restrict__ s_l,
    const int* __restrict__ cursor, const int* __restrict__ list,
    float* __restrict__ out, int N)
{
    const int t = blockIdx.x * 256 + threadIdx.x;
    const int node = t >> 6;
    if (node >= N) return;
    const int lane = threadIdx.x & 63;
    const int e2   = lane >> 4;
    const int hq   = lane & 15;
    const int head = hq >> 2;
    const int quad = hq & 3;

    int deg = cursor[node];
    deg = (deg > CAP) ? CAP : deg;

    const float4 qv = *(const float4*)(Q + (size_t)node * 64 + (hq << 2));
    const float slv = (quad < 3) ? s_l[(size_t)node * SL_DIM + head * 3 + quad] : 0.f;

    const int* lbase = list + ((size_t)node << 6);

    float4 accV = make_float4(0.f, 0.f, 0.f, 0.f);
    float zs = 0.f;

    const int ng = (deg + 3) >> 2;
#pragma unroll 2
    for (int i = 0; i < ng; ++i) {
        const int slot  = (i << 2) + e2;
        const bool valid = slot < deg;
        const int sidx  = lbase[valid ? slot : 0];

        const uint4 kv = *(const uint4*)(KV + (size_t)sidx * 64 + (hq << 2));
        const float a  = (quad < 3) ? s_l[(size_t)sidx * SL_DIM + head * 3 + quad] : 0.f;

        float dt = __uint_as_float(kv.x << 16) * qv.x
                 + __uint_as_float(kv.y << 16) * qv.y
                 + __uint_as_float(kv.z << 16) * qv.z
                 + __uint_as_float(kv.w << 16) * qv.w;
        const float df = a - slv;
        float ds = df * df;

        dt += __shfl_xor(dt, 1, 4);
        dt += __shfl_xor(dt, 2, 4);
        ds += __shfl_xor(ds, 1, 4);
        ds += __shfl_xor(ds, 2, 4);

        const float sc = fminf(fmaxf(dt * 0.25f, -5.f), 5.f);
        float score = __expf(sc);
        score = valid ? score : 0.f;
        const float w    = __expf(-ds * ds);
        const float news = score * w;
        zs += score;

        accV.x += __uint_as_float(kv.x & 0xFFFF0000u) * news;
        accV.y += __uint_as_float(kv.y & 0xFFFF0000u) * news;
        accV.z += __uint_as_float(kv.z & 0xFFFF0000u) * news;
        accV.w += __uint_as_float(kv.w & 0xFFFF0000u) * news;
    }

#pragma unroll
    for (int m = 16; m <= 32; m <<= 1) {
        accV.x += __shfl_xor(accV.x, m);
        accV.y += __shfl_xor(accV.y, m);
        accV.z += __shfl_xor(accV.z, m);
        accV.w += __shfl_xor(accV.w, m);
        zs     += __shfl_xor(zs, m);
    }

    if (e2 == 0) {
        const float inv = (zs > 0.f) ? (1.f / zs) : 1.f;
        float4 o;
        o.x = accV.x * inv; o.y = accV.y * inv;
        o.z = accV.z * inv; o.w = accV.w * inv;
        *(float4*)(out + (size_t)node * 64 + (hq << 2)) = o;
    }
}

extern "C" void kernel_launch(void* const* d_in, const int* in_sizes, int n_in,
                              void* d_out, int out_size, void* d_ws, size_t ws_size,
                              hipStream_t stream) {
    const float* h   = (const float*)d_in[0];
    const float* s_l = (const float*)d_in[1];
    const float* Wq  = (const float*)d_in[2];
    const float* bq  = (const float*)d_in[3];
    const float* Wk  = (const float*)d_in[4];
    const float* bk  = (const float*)d_in[5];
    const float* Wv  = (const float*)d_in[6];
    const float* bv  = (const float*)d_in[7];
    const int*   src = (const int*)d_in[8];
    const int*   dst = (const int*)d_in[9];
    float* out = (float*)d_out;

    const int N = in_sizes[0] / 64;   // 50000
    const int E = in_sizes[8];        // 800000

    // workspace: Q fp32 (N*64) | KV packed (N*64) | cursor (N) | list (N*CAP)
    float*    Q      = (float*)d_ws;
    unsigned* KV     = (unsigned*)(Q + (size_t)N * NODES_DIM);
    int*      cursor = (int*)(KV + (size_t)N * NODES_DIM);
    int*      list   = cursor + N;

    hipMemsetAsync(cursor, 0, (size_t)N * sizeof(int), stream);

    // heterogeneous grid: 2/3 qkv blocks (32 rows each), 1/3 fill blocks
    const int qbc = (N + 31) / 32;            // 1563
    const int fbc = (E + 1023) / 1024;        // 782
    const int g3  = ((qbc + 1) / 2 > fbc) ? (qbc + 1) / 2 : fbc;
    qkv_fill_kernel<<<3 * g3, 256, 0, stream>>>(
        h, Wq, bq, Wk, bk, Wv, bv, Q, KV, N,
        src, dst, cursor, list, E);

    const long long nthreads = (long long)N * 64;
    node_kernel<<<(int)((nthreads + 255) / 256), 256, 0, stream>>>(
        Q, KV, s_l, cursor, list, out, N);
}

// Round 5
// 175.046 us; speedup vs baseline: 1.4702x; 1.1064x over previous
//
#include <hip/hip_runtime.h>
#include <hip/hip_bf16.h>

#define NODES_DIM 64   // H*D = 4*16
#define SL_DIM    12   // H*DC = 4*3
#define CAP       64   // bucket capacity; deg ~ Poisson(16), P(>=64) ~ 1e-18

// round-to-nearest-even fp32 -> bf16
__device__ __forceinline__ unsigned short f2bf(float f) {
    union { float f; unsigned u; } x; x.f = f;
    const unsigned r = x.u + 0x7FFFu + ((x.u >> 16) & 1u);
    return (unsigned short)(r >> 16);
}

// ---------------------------------------------------------------------------
// R0 heterogeneous skeleton (best measured: 58 us qkv) with ONE isolated
// change: the GEMM's h loads are software-pipelined 2-deep (hA/hB float4[8]
// register buffers, statically indexed). R0 issued step-k4's 8 wave-uniform
// loads inside step k4 and consumed them immediately -> every wave stalled
// ~300-400cy per k4 and the 3 co-resident waves convoyed (VALUBusy 25%,
// per-k4 wall ~2300cy for 192cy of FMA issue). Now loads for k4+1 are in
// flight while k4 computes, and the first buffer is issued BEFORE W staging
// so its miss hides under staging+barrier. Inner loop stays FMA-only (R4
// proved readlane broadcast serializes: VALU time tripled).
// Roles by blockIdx%3: r in {0,1} -> QKV (VALU-bound), r==2 -> edge-bucket
// fill (atomic/latency-bound). Disjoint pipes overlap on co-resident CUs.
// ---------------------------------------------------------------------------
__global__ __launch_bounds__(256) void qkv_fill_kernel(
    const float* __restrict__ h,
    const float* __restrict__ Wq, const float* __restrict__ bq,
    const float* __restrict__ Wk, const float* __restrict__ bk,
    const float* __restrict__ Wv, const float* __restrict__ bv,
    float* __restrict__ Q, unsigned* __restrict__ KV, int N,
    const int* __restrict__ src, const int* __restrict__ dst,
    int* __restrict__ cursor, int* __restrict__ list, int E)
{
    __shared__ float sW[3][64][64];   // 48 KB (qkv role only) -> 3 blocks/CU

    const int r = blockIdx.x % 3;
    const int g = blockIdx.x / 3;

    if (r == 2) {
        // ---------------- fill role (verbatim from the 58 us R0) ----------
        const int e0 = g * 1024 + threadIdx.x;
        int sv[4], dv[4];
        bool ok[4];
#pragma unroll
        for (int j = 0; j < 4; ++j) {
            const int e = e0 + j * 256;
            ok[j] = e < E;
            sv[j] = ok[j] ? src[e] : 0;
            dv[j] = ok[j] ? dst[e] : 0;
        }
#pragma unroll
        for (int j = 0; j < 4; ++j) {
            if (ok[j]) {
                const int pos = atomicAdd(&cursor[dv[j]], 1);
                if (pos < CAP) list[((size_t)dv[j] << 6) + pos] = sv[j];
            }
        }
        return;
    }

    // ---------------- qkv role ----------------
    const int qb = g * 2 + r;
    const int rowBase0 = qb * 32;
    if (rowBase0 >= N) return;

    const int c    = threadIdx.x & 63;
    const int slot = __builtin_amdgcn_readfirstlane((int)(threadIdx.x >> 6));
    const int rowBase = rowBase0 + slot * 8;
    const bool rowsOk = rowBase < N;
    const int nrows = rowsOk ? ((N - rowBase < 8) ? (N - rowBase) : 8) : 0;

    const float4* hb = (const float4*)(h + (size_t)rowBase * 64);

    // ---- prologue: issue hA (k4=0) BEFORE W staging so the first-miss
    //      latency hides under the staging loads + barrier ----
    float4 hA[8], hB[8];
#pragma unroll
    for (int rr = 0; rr < 8; ++rr)
        hA[rr] = make_float4(0.f, 0.f, 0.f, 0.f);
    if (nrows == 8) {
#pragma unroll
        for (int rr = 0; rr < 8; ++rr) hA[rr] = hb[rr * 16];
    }

    // ---- stage W into LDS, float4-vectorized ----
    {
        float4* lf = (float4*)(&sW[0][0][0]);
        const float4* gq = (const float4*)Wq;   // 1024 float4 each
        const float4* gk = (const float4*)Wk;
        const float4* gv = (const float4*)Wv;
        for (int i = threadIdx.x; i < 1024; i += 256) {
            lf[i]        = gq[i];
            lf[i + 1024] = gk[i];
            lf[i + 2048] = gv[i];
        }
    }
    __syncthreads();

    if (!rowsOk) return;

    float acc0[8], acc1[8], acc2[8];
#pragma unroll
    for (int rr = 0; rr < 8; ++rr) { acc0[rr] = 0.f; acc1[rr] = 0.f; acc2[rr] = 0.f; }

#define QKV_COMPUTE(BUF, K4)                                          \
    {                                                                 \
        _Pragma("unroll")                                             \
        for (int kk = 0; kk < 4; ++kk) {                              \
            const int k = (K4) * 4 + kk;                              \
            const float wq = sW[0][k][c];                             \
            const float wk = sW[1][k][c];                             \
            const float wv = sW[2][k][c];                             \
            _Pragma("unroll")                                         \
            for (int rr = 0; rr < 8; ++rr) {                          \
                const float hh = (&BUF[rr].x)[kk];                    \
                acc0[rr] += hh * wq;                                  \
                acc1[rr] += hh * wk;                                  \
                acc2[rr] += hh * wv;                                  \
            }                                                         \
        }                                                             \
    }

    if (nrows == 8) {
        // steady-state: while computing from one buffer, the other's 8
        // loads are in flight (compiler emits partial vmcnt waits).
        for (int k4 = 0; k4 < 16; k4 += 2) {
#pragma unroll
            for (int rr = 0; rr < 8; ++rr) hB[rr] = hb[rr * 16 + k4 + 1];
            QKV_COMPUTE(hA, k4)
            if (k4 + 2 < 16) {
#pragma unroll
                for (int rr = 0; rr < 8; ++rr) hA[rr] = hb[rr * 16 + k4 + 2];
            }
            QKV_COMPUTE(hB, k4 + 1)
        }
    } else {
        // tail path (rare): original non-pipelined loop
        for (int k4 = 0; k4 < 16; ++k4) {
            float4 hv[8];
#pragma unroll
            for (int rr = 0; rr < 8; ++rr)
                hv[rr] = (rr < nrows)
                    ? ((const float4*)(h + (size_t)(rowBase + rr) * 64))[k4]
                    : make_float4(0.f, 0.f, 0.f, 0.f);
            QKV_COMPUTE(hv, k4)
        }
    }
#undef QKV_COMPUTE

    const float bqc = bq[c], bkc = bk[c], bvc = bv[c];
#pragma unroll
    for (int rr = 0; rr < 8; ++rr) {
        if (rr < nrows) {
            const size_t o = (size_t)(rowBase + rr) * 64 + c;
            Q[o] = acc0[rr] + bqc;
            const unsigned short kb = f2bf(acc1[rr] + bkc);
            const unsigned short vb = f2bf(acc2[rr] + bvc);
            KV[o] = ((unsigned)vb << 16) | (unsigned)kb;
        }
    }
}

// ---------------------------------------------------------------------------
// Node phase, edge-quad layout (unchanged from R0). One wave per node.
// lane = e2*16 + head*4 + quad. Per 4-edge group: 1 dwordx4 KV load/lane,
// width-4 2-stage shfl reduce, exp amortized, V accumulated in-lane.
// ---------------------------------------------------------------------------
__global__ __launch_bounds__(256) void node_kernel(
    const float* __restrict__ Q, const unsigned* __restrict__ KV,
    const float* __restrict__ s_l,
    const int* __restrict__ cursor, const int* __restrict__ list,
    float* __restrict__ out, int N)
{
    const int t = blockIdx.x * 256 + threadIdx.x;
    const int node = t >> 6;
    if (node >= N) return;
    const int lane = threadIdx.x & 63;
    const int e2   = lane >> 4;
    const int hq   = lane & 15;
    const int head = hq >> 2;
    const int quad = hq & 3;

    int deg = cursor[node];
    deg = (deg > CAP) ? CAP : deg;

    const float4 qv = *(const float4*)(Q + (size_t)node * 64 + (hq << 2));
    const float slv = (quad < 3) ? s_l[(size_t)node * SL_DIM + head * 3 + quad] : 0.f;

    const int* lbase = list + ((size_t)node << 6);

    float4 accV = make_float4(0.f, 0.f, 0.f, 0.f);
    float zs = 0.f;

    const int ng = (deg + 3) >> 2;
#pragma unroll 2
    for (int i = 0; i < ng; ++i) {
        const int slot  = (i << 2) + e2;
        const bool valid = slot < deg;
        const int sidx  = lbase[valid ? slot : 0];

        const uint4 kv = *(const uint4*)(KV + (size_t)sidx * 64 + (hq << 2));
        const float a  = (quad < 3) ? s_l[(size_t)sidx * SL_DIM + head * 3 + quad] : 0.f;

        float dt = __uint_as_float(kv.x << 16) * qv.x
                 + __uint_as_float(kv.y << 16) * qv.y
                 + __uint_as_float(kv.z << 16) * qv.z
                 + __uint_as_float(kv.w << 16) * qv.w;
        const float df = a - slv;
        float ds = df * df;

        dt += __shfl_xor(dt, 1, 4);
        dt += __shfl_xor(dt, 2, 4);
        ds += __shfl_xor(ds, 1, 4);
        ds += __shfl_xor(ds, 2, 4);

        const float sc = fminf(fmaxf(dt * 0.25f, -5.f), 5.f);
        float score = __expf(sc);
        score = valid ? score : 0.f;
        const float w    = __expf(-ds * ds);
        const float news = score * w;
        zs += score;

        accV.x += __uint_as_float(kv.x & 0xFFFF0000u) * news;
        accV.y += __uint_as_float(kv.y & 0xFFFF0000u) * news;
        accV.z += __uint_as_float(kv.z & 0xFFFF0000u) * news;
        accV.w += __uint_as_float(kv.w & 0xFFFF0000u) * news;
    }

#pragma unroll
    for (int m = 16; m <= 32; m <<= 1) {
        accV.x += __shfl_xor(accV.x, m);
        accV.y += __shfl_xor(accV.y, m);
        accV.z += __shfl_xor(accV.z, m);
        accV.w += __shfl_xor(accV.w, m);
        zs     += __shfl_xor(zs, m);
    }

    if (e2 == 0) {
        const float inv = (zs > 0.f) ? (1.f / zs) : 1.f;
        float4 o;
        o.x = accV.x * inv; o.y = accV.y * inv;
        o.z = accV.z * inv; o.w = accV.w * inv;
        *(float4*)(out + (size_t)node * 64 + (hq << 2)) = o;
    }
}

extern "C" void kernel_launch(void* const* d_in, const int* in_sizes, int n_in,
                              void* d_out, int out_size, void* d_ws, size_t ws_size,
                              hipStream_t stream) {
    const float* h   = (const float*)d_in[0];
    const float* s_l = (const float*)d_in[1];
    const float* Wq  = (const float*)d_in[2];
    const float* bq  = (const float*)d_in[3];
    const float* Wk  = (const float*)d_in[4];
    const float* bk  = (const float*)d_in[5];
    const float* Wv  = (const float*)d_in[6];
    const float* bv  = (const float*)d_in[7];
    const int*   src = (const int*)d_in[8];
    const int*   dst = (const int*)d_in[9];
    float* out = (float*)d_out;

    const int N = in_sizes[0] / 64;   // 50000
    const int E = in_sizes[8];        // 800000

    // workspace: Q fp32 (N*64) | KV packed (N*64) | cursor (N) | list (N*CAP)
    float*    Q      = (float*)d_ws;
    unsigned* KV     = (unsigned*)(Q + (size_t)N * NODES_DIM);
    int*      cursor = (int*)(KV + (size_t)N * NODES_DIM);
    int*      list   = cursor + N;

    hipMemsetAsync(cursor, 0, (size_t)N * sizeof(int), stream);

    // heterogeneous grid: 2/3 qkv blocks (32 rows each), 1/3 fill blocks
    const int qbc = (N + 31) / 32;            // 1563
    const int fbc = (E + 1023) / 1024;        // 782
    const int g3  = ((qbc + 1) / 2 > fbc) ? (qbc + 1) / 2 : fbc;
    qkv_fill_kernel<<<3 * g3, 256, 0, stream>>>(
        h, Wq, bq, Wk, bk, Wv, bv, Q, KV, N,
        src, dst, cursor, list, E);

    const long long nthreads = (long long)N * 64;
    node_kernel<<<(int)((nthreads + 255) / 256), 256, 0, stream>>>(
        Q, KV, s_l, cursor, list, out, N);
}